// Round 1
// baseline (198.462 us; speedup 1.0000x reference)
//
#include <hip/hip_runtime.h>

#define HH 128
#define WW 128
#define WIN 16

// One 64-lane wave per (n,c) plane. Thread t owns rows 2t and 2t+1.
// Carry = previous column's H values (hp0, hp1) in registers.
// Neighbor exchange via wave shuffles (no LDS, no barriers).
__global__ __launch_bounds__(64) void gr2d_kernel(
    const float* __restrict__ X, const float* __restrict__ Bm,
    const float* __restrict__ G1, const float* __restrict__ G2,
    const float* __restrict__ G3, float* __restrict__ Out)
{
    const int t = threadIdx.x;                       // 0..63
    const size_t pb = (size_t)blockIdx.x * (HH * WW);
    const size_t b0 = pb + (size_t)(2 * t) * WW;     // row 2t
    const size_t b1 = b0 + WW;                       // row 2t+1

    float hp0 = 0.f, hp1 = 0.f;                      // H[2t, w-1], H[2t+1, w-1]

    for (int win = 0; win < WW / WIN; ++win) {
        const int wb = win * WIN;

        // ---- burst-load this window: 5 inputs x 2 rows x WIN floats ----
        float bx0[WIN], bx1[WIN];                    // fused B*X
        float a0[WIN], a1[WIN];                      // G1
        float c0[WIN], c1[WIN];                      // G2
        float d0[WIN], d1[WIN];                      // G3
        #pragma unroll
        for (int j = 0; j < WIN / 4; ++j) {
            const size_t o0 = b0 + wb + 4 * j;
            const size_t o1 = b1 + wb + 4 * j;
            const float4 x0 = *reinterpret_cast<const float4*>(X  + o0);
            const float4 x1 = *reinterpret_cast<const float4*>(X  + o1);
            const float4 v0 = *reinterpret_cast<const float4*>(Bm + o0);
            const float4 v1 = *reinterpret_cast<const float4*>(Bm + o1);
            const float4 p0 = *reinterpret_cast<const float4*>(G1 + o0);
            const float4 p1 = *reinterpret_cast<const float4*>(G1 + o1);
            const float4 q0 = *reinterpret_cast<const float4*>(G2 + o0);
            const float4 q1 = *reinterpret_cast<const float4*>(G2 + o1);
            const float4 r0 = *reinterpret_cast<const float4*>(G3 + o0);
            const float4 r1 = *reinterpret_cast<const float4*>(G3 + o1);

            bx0[4*j+0] = v0.x * x0.x; bx0[4*j+1] = v0.y * x0.y;
            bx0[4*j+2] = v0.z * x0.z; bx0[4*j+3] = v0.w * x0.w;
            bx1[4*j+0] = v1.x * x1.x; bx1[4*j+1] = v1.y * x1.y;
            bx1[4*j+2] = v1.z * x1.z; bx1[4*j+3] = v1.w * x1.w;

            a0[4*j+0] = p0.x; a0[4*j+1] = p0.y; a0[4*j+2] = p0.z; a0[4*j+3] = p0.w;
            a1[4*j+0] = p1.x; a1[4*j+1] = p1.y; a1[4*j+2] = p1.z; a1[4*j+3] = p1.w;
            c0[4*j+0] = q0.x; c0[4*j+1] = q0.y; c0[4*j+2] = q0.z; c0[4*j+3] = q0.w;
            c1[4*j+0] = q1.x; c1[4*j+1] = q1.y; c1[4*j+2] = q1.z; c1[4*j+3] = q1.w;
            d0[4*j+0] = r0.x; d0[4*j+1] = r0.y; d0[4*j+2] = r0.z; d0[4*j+3] = r0.w;
            d1[4*j+0] = r1.x; d1[4*j+1] = r1.y; d1[4*j+2] = r1.z; d1[4*j+3] = r1.w;
        }

        // ---- sequential scan over the window ----
        float o0v[WIN], o1v[WIN];
        #pragma unroll
        for (int k = 0; k < WIN; ++k) {
            // Use OLD carries for the cross-lane exchange.
            float up0 = __shfl_up(hp1, 1);    // H[2t-1, w-1] from thread t-1
            float dn1 = __shfl_down(hp0, 1);  // H[2t+2, w-1] from thread t+1
            if (t == 0)  up0 = 0.f;           // row 0 has no upper neighbor
            if (t == 63) dn1 = 0.f;           // row 127 has no lower neighbor

            const float h0 = bx0[k] + a0[k] * up0 + c0[k] * hp0 + d0[k] * hp1;
            const float h1 = bx1[k] + a1[k] * hp0 + c1[k] * hp1 + d1[k] * dn1;
            hp0 = h0; hp1 = h1;
            o0v[k] = h0; o1v[k] = h1;
        }

        // ---- store window ----
        #pragma unroll
        for (int j = 0; j < WIN / 4; ++j) {
            *reinterpret_cast<float4*>(Out + b0 + wb + 4 * j) =
                make_float4(o0v[4*j], o0v[4*j+1], o0v[4*j+2], o0v[4*j+3]);
            *reinterpret_cast<float4*>(Out + b1 + wb + 4 * j) =
                make_float4(o1v[4*j], o1v[4*j+1], o1v[4*j+2], o1v[4*j+3]);
        }
    }
}

extern "C" void kernel_launch(void* const* d_in, const int* in_sizes, int n_in,
                              void* d_out, int out_size, void* d_ws, size_t ws_size,
                              hipStream_t stream) {
    const float* X  = (const float*)d_in[0];
    const float* Bm = (const float*)d_in[1];
    const float* G1 = (const float*)d_in[2];
    const float* G2 = (const float*)d_in[3];
    const float* G3 = (const float*)d_in[4];
    float* Out = (float*)d_out;

    const int planes = in_sizes[0] / (HH * WW);   // 8*96 = 768
    gr2d_kernel<<<dim3(planes), dim3(64), 0, stream>>>(X, Bm, G1, G2, G3, Out);
}

// Round 2
// 133.789 us; speedup vs baseline: 1.4834x; 1.4834x over previous
//
#include <hip/hip_runtime.h>

#define HH 128
#define WW 128
#define SW 32            // superwindow: 128B per row per input -> full L2 lines
#define NJ (SW / 4)      // float4s per row per superwindow

// One 64-lane wave per (n,c) plane. Thread t owns rows 2t and 2t+1.
// Carry = previous column's H (hp0, hp1) in registers; h-stencil neighbor
// exchange via wave shuffles. All loads of a superwindow are batched ahead
// of a sched_barrier so ~80 float4 loads are in flight per wave (the only
// latency-hiding available at 0.75 waves/SIMD).
__global__ __launch_bounds__(64, 1) void gr2d_kernel(
    const float* __restrict__ X, const float* __restrict__ Bm,
    const float* __restrict__ G1, const float* __restrict__ G2,
    const float* __restrict__ G3, float* __restrict__ Out)
{
    const int t = threadIdx.x;                       // 0..63
    const size_t pb = (size_t)blockIdx.x * (HH * WW);
    const size_t b0 = pb + (size_t)(2 * t) * WW;     // row 2t
    const size_t b1 = b0 + WW;                       // row 2t+1

    float hp0 = 0.f, hp1 = 0.f;                      // H[2t, w-1], H[2t+1, w-1]

    for (int sw = 0; sw < WW / SW; ++sw) {
        const int wb = sw * SW;

        // ---- phase 1: issue ALL loads for this superwindow ----
        float4 xv0[NJ], xv1[NJ], bv0[NJ], bv1[NJ];
        float4 av0[NJ], av1[NJ], cv0[NJ], cv1[NJ], dv0[NJ], dv1[NJ];
        #pragma unroll
        for (int j = 0; j < NJ; ++j) {
            const size_t o0 = b0 + wb + 4 * j;
            const size_t o1 = b1 + wb + 4 * j;
            xv0[j] = *reinterpret_cast<const float4*>(X  + o0);
            xv1[j] = *reinterpret_cast<const float4*>(X  + o1);
            bv0[j] = *reinterpret_cast<const float4*>(Bm + o0);
            bv1[j] = *reinterpret_cast<const float4*>(Bm + o1);
            av0[j] = *reinterpret_cast<const float4*>(G1 + o0);
            av1[j] = *reinterpret_cast<const float4*>(G1 + o1);
            cv0[j] = *reinterpret_cast<const float4*>(G2 + o0);
            cv1[j] = *reinterpret_cast<const float4*>(G2 + o1);
            dv0[j] = *reinterpret_cast<const float4*>(G3 + o0);
            dv1[j] = *reinterpret_cast<const float4*>(G3 + o1);
        }
        __builtin_amdgcn_sched_barrier(0);   // keep all loads above this point

        // ---- phase 2: fuse bx = B*X in place (frees bv; xv becomes bx) ----
        #pragma unroll
        for (int j = 0; j < NJ; ++j) {
            xv0[j].x *= bv0[j].x; xv0[j].y *= bv0[j].y;
            xv0[j].z *= bv0[j].z; xv0[j].w *= bv0[j].w;
            xv1[j].x *= bv1[j].x; xv1[j].y *= bv1[j].y;
            xv1[j].z *= bv1[j].z; xv1[j].w *= bv1[j].w;
        }

        // ---- phase 3: sequential scan; outputs overwrite xv in place ----
        auto step = [&](float& bx0, float a0, float c0, float d0,
                        float& bx1, float a1, float c1, float d1) {
            float up0 = __shfl_up(hp1, 1);    // H[2t-1, w-1] from thread t-1
            float dn1 = __shfl_down(hp0, 1);  // H[2t+2, w-1] from thread t+1
            if (t == 0)  up0 = 0.f;
            if (t == 63) dn1 = 0.f;
            const float h0 = bx0 + a0 * up0 + c0 * hp0 + d0 * hp1;
            const float h1 = bx1 + a1 * hp0 + c1 * hp1 + d1 * dn1;
            hp0 = h0; hp1 = h1;
            bx0 = h0; bx1 = h1;
        };
        #pragma unroll
        for (int j = 0; j < NJ; ++j) {
            step(xv0[j].x, av0[j].x, cv0[j].x, dv0[j].x,
                 xv1[j].x, av1[j].x, cv1[j].x, dv1[j].x);
            step(xv0[j].y, av0[j].y, cv0[j].y, dv0[j].y,
                 xv1[j].y, av1[j].y, cv1[j].y, dv1[j].y);
            step(xv0[j].z, av0[j].z, cv0[j].z, dv0[j].z,
                 xv1[j].z, av1[j].z, cv1[j].z, dv1[j].z);
            step(xv0[j].w, av0[j].w, cv0[j].w, dv0[j].w,
                 xv1[j].w, av1[j].w, cv1[j].w, dv1[j].w);
        }

        // ---- phase 4: store superwindow (full 128B lines per row) ----
        #pragma unroll
        for (int j = 0; j < NJ; ++j) {
            *reinterpret_cast<float4*>(Out + b0 + wb + 4 * j) = xv0[j];
            *reinterpret_cast<float4*>(Out + b1 + wb + 4 * j) = xv1[j];
        }
    }
}

extern "C" void kernel_launch(void* const* d_in, const int* in_sizes, int n_in,
                              void* d_out, int out_size, void* d_ws, size_t ws_size,
                              hipStream_t stream) {
    const float* X  = (const float*)d_in[0];
    const float* Bm = (const float*)d_in[1];
    const float* G1 = (const float*)d_in[2];
    const float* G2 = (const float*)d_in[3];
    const float* G3 = (const float*)d_in[4];
    float* Out = (float*)d_out;

    const int planes = in_sizes[0] / (HH * WW);   // 8*96 = 768
    gr2d_kernel<<<dim3(planes), dim3(64), 0, stream>>>(X, Bm, G1, G2, G3, Out);
}

// Round 3
// 67.578 us; speedup vs baseline: 2.9368x; 1.9798x over previous
//
#include <hip/hip_runtime.h>

#define HH 128
#define WW 128
#define SW 32            // 32 cols/superwindow: 128B per row per input = full lines

// 2 waves per (n,c) plane, 1 row per thread (t = row, 0..127).
// Carry hp = H[row, w-1] in a register. Row stencil: __shfl within wave;
// the single wave0/wave1 boundary (rows 63/64) goes through a 4-float LDS
// halo with parity double-buffering and ONE raw s_barrier per step
// (lgkmcnt-only wait; no vmcnt drain so global stores stay in flight).
// All 40 float4 loads of a superwindow are NAMED registers issued before a
// sched_barrier(0): ~640B in flight per wave is the only latency hiding
// available at 1.5 waves/SIMD.
__global__ __launch_bounds__(128, 2) void gr2d_kernel(
    const float* __restrict__ X, const float* __restrict__ Bm,
    const float* __restrict__ G1, const float* __restrict__ G2,
    const float* __restrict__ G3, float* __restrict__ Out)
{
    const int t = threadIdx.x;                               // row index 0..127
    const size_t rb = (size_t)blockIdx.x * (HH * WW) + (size_t)t * WW;

    __shared__ float halo[2][2];   // [parity][0: H[63,w-1], 1: H[64,w-1]]
    if (t == 0) { halo[0][0] = 0.f; halo[0][1] = 0.f; }
    __syncthreads();

    float hp = 0.f;

    for (int sw = 0; sw < WW / SW; ++sw) {
        const float* xp = X  + rb + sw * SW;
        const float* bp = Bm + rb + sw * SW;
        const float* ap = G1 + rb + sw * SW;
        const float* cp = G2 + rb + sw * SW;
        const float* dp = G3 + rb + sw * SW;

#define LDJ(p, j) (*reinterpret_cast<const float4*>((p) + 4 * (j)))
        // ---- phase 1: 40 named float4 loads, all issued up front ----
        float4 xv0 = LDJ(xp,0), xv1 = LDJ(xp,1), xv2 = LDJ(xp,2), xv3 = LDJ(xp,3),
               xv4 = LDJ(xp,4), xv5 = LDJ(xp,5), xv6 = LDJ(xp,6), xv7 = LDJ(xp,7);
        float4 bv0 = LDJ(bp,0), bv1 = LDJ(bp,1), bv2 = LDJ(bp,2), bv3 = LDJ(bp,3),
               bv4 = LDJ(bp,4), bv5 = LDJ(bp,5), bv6 = LDJ(bp,6), bv7 = LDJ(bp,7);
        float4 av0 = LDJ(ap,0), av1 = LDJ(ap,1), av2 = LDJ(ap,2), av3 = LDJ(ap,3),
               av4 = LDJ(ap,4), av5 = LDJ(ap,5), av6 = LDJ(ap,6), av7 = LDJ(ap,7);
        float4 cv0 = LDJ(cp,0), cv1 = LDJ(cp,1), cv2 = LDJ(cp,2), cv3 = LDJ(cp,3),
               cv4 = LDJ(cp,4), cv5 = LDJ(cp,5), cv6 = LDJ(cp,6), cv7 = LDJ(cp,7);
        float4 dv0 = LDJ(dp,0), dv1 = LDJ(dp,1), dv2 = LDJ(dp,2), dv3 = LDJ(dp,3),
               dv4 = LDJ(dp,4), dv5 = LDJ(dp,5), dv6 = LDJ(dp,6), dv7 = LDJ(dp,7);
        __builtin_amdgcn_sched_barrier(0);   // nothing crosses: loads stay batched

        // ---- phase 2: fuse bx = B*X in place; bv* die here ----
#define MUL4(a, b) a.x *= b.x; a.y *= b.y; a.z *= b.z; a.w *= b.w;
        MUL4(xv0, bv0) MUL4(xv1, bv1) MUL4(xv2, bv2) MUL4(xv3, bv3)
        MUL4(xv4, bv4) MUL4(xv5, bv5) MUL4(xv6, bv6) MUL4(xv7, bv7)

        // ---- phase 3: 32 sequential scan steps; outputs overwrite xv in place ----
#define STEP(xc, ac, cc, dc, par) do {                                      \
        float up = __shfl_up(hp, 1);                                        \
        float dn = __shfl_down(hp, 1);                                      \
        if (t == 63)  dn = halo[par][1];                                    \
        if (t == 64)  up = halo[par][0];                                    \
        if (t == 0)   up = 0.f;                                             \
        if (t == 127) dn = 0.f;                                             \
        const float h = xc + ac * up + cc * hp + dc * dn;                   \
        if (t == 63) halo[(par) ^ 1][0] = h;                                \
        if (t == 64) halo[(par) ^ 1][1] = h;                                \
        asm volatile("s_waitcnt lgkmcnt(0)" ::: "memory");                  \
        __builtin_amdgcn_s_barrier();                                       \
        hp = h; xc = h;                                                     \
    } while (0)

#define STEP4(v)                                                            \
        STEP(xv##v.x, av##v.x, cv##v.x, dv##v.x, 0);                        \
        STEP(xv##v.y, av##v.y, cv##v.y, dv##v.y, 1);                        \
        STEP(xv##v.z, av##v.z, cv##v.z, dv##v.z, 0);                        \
        STEP(xv##v.w, av##v.w, cv##v.w, dv##v.w, 1);

        STEP4(0) STEP4(1) STEP4(2) STEP4(3)
        STEP4(4) STEP4(5) STEP4(6) STEP4(7)

        // ---- phase 4: store superwindow (full 128B line per row) ----
        float* op = Out + rb + sw * SW;
        *reinterpret_cast<float4*>(op + 0)  = xv0;
        *reinterpret_cast<float4*>(op + 4)  = xv1;
        *reinterpret_cast<float4*>(op + 8)  = xv2;
        *reinterpret_cast<float4*>(op + 12) = xv3;
        *reinterpret_cast<float4*>(op + 16) = xv4;
        *reinterpret_cast<float4*>(op + 20) = xv5;
        *reinterpret_cast<float4*>(op + 24) = xv6;
        *reinterpret_cast<float4*>(op + 28) = xv7;
    }
}

extern "C" void kernel_launch(void* const* d_in, const int* in_sizes, int n_in,
                              void* d_out, int out_size, void* d_ws, size_t ws_size,
                              hipStream_t stream) {
    const float* X  = (const float*)d_in[0];
    const float* Bm = (const float*)d_in[1];
    const float* G1 = (const float*)d_in[2];
    const float* G2 = (const float*)d_in[3];
    const float* G3 = (const float*)d_in[4];
    float* Out = (float*)d_out;

    const int planes = in_sizes[0] / (HH * WW);   // 8*96 = 768
    gr2d_kernel<<<dim3(planes), dim3(128), 0, stream>>>(X, Bm, G1, G2, G3, Out);
}